// Round 1
// 187.238 us; speedup vs baseline: 1.0025x; 1.0025x over previous
//
#include <hip/hip_runtime.h>
#include <math.h>

#define D 2048
#define EPS_COS 1e-8f
#define EPS_DEN 1e-6f
#define INV_TEMP 10.0f
#define TPB 256
#define WPB 4                   // waves per block, 1 row per wave
#define NBLK 4096               // 4096 blocks * 4 rows = 16384 rows

// pos_pair: reference declares int64 but JAX x64-off makes it int32.
// Hedge: accept int32 reading iff plausible (in range, i != j), else int64.
__device__ __forceinline__ void get_ij(const int* __restrict__ p, int n,
                                       int& i, int& j) {
    int i32 = p[0], j32 = p[1];
    if (i32 >= 0 && i32 < n && j32 >= 0 && j32 < n && i32 != j32) {
        i = i32; j = j32; return;
    }
    const long long* p64 = (const long long*)p;
    i = (int)p64[0]; j = (int)p64[1];
}

// Kernel 1: one row per wave. xi is staged in LDS ONCE per block (vs once
// per wave in registers before): halves VMEM issue, cuts xi L2 traffic 4x,
// frees ~32 VGPRs of load buffer -> higher occupancy for ramp/tail.
// Issue order: xi loads (2/thread) FIRST, then row loads (8/lane), so the
// ds_write only drains the xi loads (vmcnt(8)) and the row loads remain in
// flight across the barrier.
__global__ __launch_bounds__(TPB)
void e_kernel(const float* __restrict__ x, const int* __restrict__ pos,
              float* __restrict__ part, float* __restrict__ nom, int n) {
    int i, j;
    get_ij(pos, n, i, j);
    const int lane = threadIdx.x & 63;
    const int wave = threadIdx.x >> 6;
    const int t    = threadIdx.x;
    const int row  = blockIdx.x * WPB + wave;

    const float4* __restrict__ xr = (const float4*)(x + (size_t)row * D);
    const float4* __restrict__ xi = (const float4*)(x + (size_t)i * D);

    __shared__ float4 s_xi[D / 4];       // 8 KB: the anchor row
    __shared__ float  s_den[WPB];

    // xi loads first (2 float4 per thread covers 512 float4)
    float4 x0 = xi[t];
    float4 x1 = xi[t + 256];

    // row loads: 8 float4 per lane, issued while xi is still in flight
    float4 a[8];
#pragma unroll
    for (int w = 0; w < 8; ++w) a[w] = xr[lane + w * 64];

    s_xi[t]       = x0;
    s_xi[t + 256] = x1;
    __syncthreads();

    float dot = 0.f, sq = 0.f, sqi = 0.f;
#pragma unroll
    for (int w = 0; w < 8; ++w) {
        const float4 b = s_xi[lane + w * 64];
        dot = fmaf(a[w].x, b.x, fmaf(a[w].y, b.y,
              fmaf(a[w].z, b.z, fmaf(a[w].w, b.w, dot))));
        sq  = fmaf(a[w].x, a[w].x, fmaf(a[w].y, a[w].y,
              fmaf(a[w].z, a[w].z, fmaf(a[w].w, a[w].w, sq))));
        sqi = fmaf(b.x, b.x, fmaf(b.y, b.y,
              fmaf(b.z, b.z, fmaf(b.w, b.w, sqi))));
    }
#pragma unroll
    for (int off = 32; off; off >>= 1) {
        dot += __shfl_down(dot, off);
        sq  += __shfl_down(sq,  off);
        sqi += __shfl_down(sqi, off);
    }

    if (lane == 0) {
        float nk = fmaxf(sqrtf(sq),  EPS_COS);
        float ni = fmaxf(sqrtf(sqi), EPS_COS);
        float e  = expf(INV_TEMP * dot / (nk * ni));
        s_den[wave] = (row != i) ? e : 0.f;   // den includes k==j, excludes k==i
        if (row == j) *nom = e;
    }
    __syncthreads();
    if (t == 0)
        part[blockIdx.x] = (s_den[0] + s_den[1]) + (s_den[2] + s_den[3]);
}

// Kernel 2: one block sums 4096 partials (16 KB) + reads nom, finishes loss.
__global__ __launch_bounds__(1024)
void loss_kernel(const float* __restrict__ part, const float* __restrict__ nom,
                 float* __restrict__ out) {
    const int t = threadIdx.x;
    const float4 v = ((const float4*)part)[t];     // 1024 float4 = 4096 floats
    float s = (v.x + v.y) + (v.z + v.w);
#pragma unroll
    for (int off = 32; off; off >>= 1) s += __shfl_down(s, off);

    __shared__ float ls[16];
    if ((t & 63) == 0) ls[t >> 6] = s;
    __syncthreads();

    if (t == 0) {
        float den = 0.f;
#pragma unroll
        for (int w = 0; w < 16; ++w) den += ls[w];
        out[0] = -logf(nom[0] / (den + EPS_DEN));
    }
}

extern "C" void kernel_launch(void* const* d_in, const int* in_sizes, int n_in,
                              void* d_out, int out_size, void* d_ws, size_t ws_size,
                              hipStream_t stream) {
    const float* x    = (const float*)d_in[0];
    const int*   pos  = (const int*)d_in[1];
    float*       out  = (float*)d_out;
    float*       part = (float*)d_ws;              // [0..4095] block partials
    float*       nom  = (float*)d_ws + NBLK;       // [4096] e_j slot

    const int n = in_sizes[0] / D;                 // 16384

    e_kernel<<<NBLK, TPB, 0, stream>>>(x, pos, part, nom, n);
    loss_kernel<<<1, 1024, 0, stream>>>(part, nom, out);
}